// Round 1
// baseline (197.010 us; speedup 1.0000x reference)
//
#include <hip/hip_runtime.h>
#include <hip/hip_bf16.h>
#include <math.h>

#define HEADS 8
#define DH 32
#define DIM 256
#define INNER 256
#define B_ 2
#define S_ 8
#define H_ 32
#define W_ 16
#define NTOK (B_*S_*H_*W_)   /* 8192 */
#define WIN 75

#define BM 64
#define BN 64
#define BK 64

// ---------------------------------------------------------------------------
// Shared 64x64 output-tile fp32 GEMM body: out[m][j] = sum_k A[m][k]*W[j][k]
// A: [M][256] row-major, W: [256-row segment][256] row-major, K=256.
// 256 threads, each computes 4x4 outputs.
// ---------------------------------------------------------------------------
__device__ __forceinline__ void gemm64_tile(
    const float* __restrict__ A, const float* __restrict__ W,
    const float* __restrict__ bias, float* __restrict__ outp,
    int m0, int j0,
    float (*at)[BM + 4], float (*wt)[BN + 4])
{
    const int tid = threadIdx.x;
    const int tx = tid & 15;
    const int ty = tid >> 4;

    float acc[4][4] = {};

    for (int k0 = 0; k0 < DIM; k0 += BK) {
        // cooperative load: each thread loads 4 float4 from A and 4 from W,
        // stored transposed into LDS ( [k][m] / [k][j] )
        const int lr = ty;        // 0..15
        const int lc = tx * 4;    // 0..60
        #pragma unroll
        for (int it = 0; it < 4; ++it) {
            const int r = lr + 16 * it;
            const float4 va = *(const float4*)(A + (size_t)(m0 + r) * DIM + k0 + lc);
            at[lc + 0][r] = va.x; at[lc + 1][r] = va.y;
            at[lc + 2][r] = va.z; at[lc + 3][r] = va.w;
            const float4 vw = *(const float4*)(W + (size_t)(j0 + r) * DIM + k0 + lc);
            wt[lc + 0][r] = vw.x; wt[lc + 1][r] = vw.y;
            wt[lc + 2][r] = vw.z; wt[lc + 3][r] = vw.w;
        }
        __syncthreads();

        #pragma unroll 8
        for (int kk = 0; kk < BK; ++kk) {
            const float a0 = at[kk][ty * 4 + 0];
            const float a1 = at[kk][ty * 4 + 1];
            const float a2 = at[kk][ty * 4 + 2];
            const float a3 = at[kk][ty * 4 + 3];
            const float b0 = wt[kk][tx * 4 + 0];
            const float b1 = wt[kk][tx * 4 + 1];
            const float b2 = wt[kk][tx * 4 + 2];
            const float b3 = wt[kk][tx * 4 + 3];
            acc[0][0] += a0 * b0; acc[0][1] += a0 * b1; acc[0][2] += a0 * b2; acc[0][3] += a0 * b3;
            acc[1][0] += a1 * b0; acc[1][1] += a1 * b1; acc[1][2] += a1 * b2; acc[1][3] += a1 * b3;
            acc[2][0] += a2 * b0; acc[2][1] += a2 * b1; acc[2][2] += a2 * b2; acc[2][3] += a2 * b3;
            acc[3][0] += a3 * b0; acc[3][1] += a3 * b1; acc[3][2] += a3 * b2; acc[3][3] += a3 * b3;
        }
        __syncthreads();
    }

    #pragma unroll
    for (int i = 0; i < 4; ++i) {
        const int row = m0 + ty * 4 + i;
        const int col = j0 + tx * 4;
        float4 o;
        o.x = acc[i][0]; o.y = acc[i][1]; o.z = acc[i][2]; o.w = acc[i][3];
        if (bias) {
            o.x += bias[col + 0]; o.y += bias[col + 1];
            o.z += bias[col + 2]; o.w += bias[col + 3];
        }
        *(float4*)(outp + (size_t)row * INNER + col) = o;
    }
}

// ---------------------------------------------------------------------------
// Kernel 1: fused q/k/v projections.  qkv layout: [3][NTOK][INNER] fp32
//   seg 0: qp = q @ wq^T,  seg 1: k = x @ wk^T,  seg 2: v = x @ wv^T
// grid = (NTOK/64, 12)  (12 = 3 segments * 256/64)
// ---------------------------------------------------------------------------
__global__ __launch_bounds__(256) void proj_kernel(
    const float* __restrict__ x, const float* __restrict__ q,
    const float* __restrict__ wq, const float* __restrict__ wk,
    const float* __restrict__ wv, float* __restrict__ qkv)
{
    __shared__ float at[BK][BM + 4];
    __shared__ float wt[BK][BN + 4];

    const int seg = blockIdx.y >> 2;   // 0,1,2
    const int jt  = blockIdx.y & 3;    // 0..3
    const float* A = (seg == 0) ? q : x;
    const float* W = (seg == 0) ? wq : ((seg == 1) ? wk : wv);
    float* outp = qkv + (size_t)seg * NTOK * INNER;

    gemm64_tile(A, W, nullptr, outp, blockIdx.x * BM, jt * BN, at, wt);
}

// ---------------------------------------------------------------------------
// Kernel 2: local-window attention per token. block = 256 thr, grid = NTOK.
// ---------------------------------------------------------------------------
__global__ __launch_bounds__(256) void attn_kernel(
    const float* __restrict__ qkv, float* __restrict__ ao)
{
    __shared__ float qrow[INNER];
    __shared__ float dots[HEADS][WIN + 5];
    __shared__ int   nwin[WIN];
    __shared__ float inv_sum[HEADS];

    const int n   = blockIdx.x;
    const int tid = threadIdx.x;
    const int wpos = n & (W_ - 1);
    const int hpos = (n >> 4) & (H_ - 1);
    const int spos = (n >> 9) & (S_ - 1);

    const float* qp    = qkv + (size_t)n * INNER;
    const float* kbase = qkv + (size_t)1 * NTOK * INNER;
    const float* vbase = qkv + (size_t)2 * NTOK * INNER;

    qrow[tid] = qp[tid];
    __syncthreads();

    const float scale = 0.17677669529663687f;  // 32^-0.5

    // phase 2: dots[h][wi] = scale * q_h . k_h(neighbor)
    for (int t = tid; t < HEADS * WIN; t += 256) {
        const int head = t / WIN;
        const int wi   = t - head * WIN;
        const int ds = wi / 25 - 1;
        const int dh = (wi / 5) % 5 - 2;
        const int dw = wi % 5 - 2;
        const int s2 = spos + ds, h2 = hpos + dh, w2 = wpos + dw;
        const bool valid = ((unsigned)s2 < S_) && ((unsigned)h2 < H_) && ((unsigned)w2 < W_);
        const int nn = n + (ds * H_ + dh) * W_ + dw;
        float d = -INFINITY;
        if (valid) {
            const float* krow = kbase + (size_t)nn * INNER + head * DH;
            const float* ql   = qrow + head * DH;
            float a = 0.f;
            #pragma unroll
            for (int dd = 0; dd < DH; ++dd) a += ql[dd] * krow[dd];
            d = a * scale;
        }
        dots[head][wi] = d;
        if (head == 0) nwin[wi] = valid ? nn : -1;
    }
    __syncthreads();

    // phase 3: softmax per head over 75, one 32-lane group per head
    {
        const int g = tid >> 5, l = tid & 31;
        const float v0 = dots[g][l];
        const float v1 = dots[g][l + 32];
        const float v2 = (l + 64 < WIN) ? dots[g][l + 64] : -INFINITY;
        float m = fmaxf(v0, fmaxf(v1, v2));
        #pragma unroll
        for (int off = 16; off; off >>= 1) m = fmaxf(m, __shfl_xor(m, off));
        const float e0 = __expf(v0 - m);
        const float e1 = __expf(v1 - m);
        const float e2 = (l + 64 < WIN) ? __expf(v2 - m) : 0.f;
        float s = e0 + e1 + e2;
        #pragma unroll
        for (int off = 16; off; off >>= 1) s += __shfl_xor(s, off);
        dots[g][l] = e0;
        dots[g][l + 32] = e1;
        if (l + 64 < WIN) dots[g][l + 64] = e2;
        if (l == 0) inv_sum[g] = 1.f / s;
    }
    __syncthreads();

    // phase 4: out[h][d] = sum_wi p[h][wi] * v[nn][h*32+d], normalized
    {
        const int head = tid >> 5, d = tid & 31;
        float acc = 0.f;
        for (int wi = 0; wi < WIN; ++wi) {
            const int nn = nwin[wi];
            if (nn >= 0)
                acc += dots[head][wi] * vbase[(size_t)nn * INNER + head * DH + d];
        }
        ao[(size_t)n * INNER + tid] = acc * inv_sum[head];
    }
}

// ---------------------------------------------------------------------------
// Kernel 3: output projection: out = ao @ wo^T + bo
// grid = (NTOK/64, 4)
// ---------------------------------------------------------------------------
__global__ __launch_bounds__(256) void outproj_kernel(
    const float* __restrict__ ao, const float* __restrict__ wo,
    const float* __restrict__ bo, float* __restrict__ out)
{
    __shared__ float at[BK][BM + 4];
    __shared__ float wt[BK][BN + 4];
    gemm64_tile(ao, wo, bo, out, blockIdx.x * BM, blockIdx.y * BN, at, wt);
}

// ---------------------------------------------------------------------------
extern "C" void kernel_launch(void* const* d_in, const int* in_sizes, int n_in,
                              void* d_out, int out_size, void* d_ws, size_t ws_size,
                              hipStream_t stream) {
    const float* x  = (const float*)d_in[0];
    const float* q  = (const float*)d_in[1];
    const float* wq = (const float*)d_in[2];
    const float* wk = (const float*)d_in[3];
    const float* wv = (const float*)d_in[4];
    const float* wo = (const float*)d_in[5];
    const float* bo = (const float*)d_in[6];
    float* out = (float*)d_out;

    // workspace: qkv [3][8192][256] f32 (24 MB) + ao [8192][256] f32 (8 MB)
    float* qkv = (float*)d_ws;
    float* ao  = qkv + (size_t)3 * NTOK * INNER;

    dim3 g1(NTOK / BM, 12);
    proj_kernel<<<g1, 256, 0, stream>>>(x, q, wq, wk, wv, qkv);

    attn_kernel<<<NTOK, 256, 0, stream>>>(qkv, ao);

    dim3 g3(NTOK / BM, INNER / BN);
    outproj_kernel<<<g3, 256, 0, stream>>>(ao, wo, bo, out);
}

// Round 2
// 142.062 us; speedup vs baseline: 1.3868x; 1.3868x over previous
//
#include <hip/hip_runtime.h>
#include <hip/hip_bf16.h>
#include <math.h>

#define HEADS 8
#define DH 32
#define DIM 256
#define INNER 256
#define B_ 2
#define S_ 8
#define H_ 32
#define W_ 16
#define NTOK (B_*S_*H_*W_)   /* 8192 */
#define WIN 75

#define BM 64
#define BN 64
#define BK 64

// halo geometry for one (b,s,h) row of 16 tokens
#define HS 3
#define HH 5
#define HW 20
#define NHALO (HS*HH*HW)     /* 300 */
#define KT_PITCH 301         /* K^T row stride (floats) — conflict-free */
#define V_PITCH 33           /* V row stride (floats) */

// ---------------------------------------------------------------------------
// Shared 64x64 output-tile fp32 GEMM body: out[m][j] = sum_k A[m][k]*W[j][k]
// ---------------------------------------------------------------------------
__device__ __forceinline__ void gemm64_tile(
    const float* __restrict__ A, const float* __restrict__ W,
    const float* __restrict__ bias, float* __restrict__ outp,
    int m0, int j0,
    float (*at)[BM + 4], float (*wt)[BN + 4])
{
    const int tid = threadIdx.x;
    const int tx = tid & 15;
    const int ty = tid >> 4;

    float acc[4][4] = {};

    for (int k0 = 0; k0 < DIM; k0 += BK) {
        const int lr = ty;
        const int lc = tx * 4;
        #pragma unroll
        for (int it = 0; it < 4; ++it) {
            const int r = lr + 16 * it;
            const float4 va = *(const float4*)(A + (size_t)(m0 + r) * DIM + k0 + lc);
            at[lc + 0][r] = va.x; at[lc + 1][r] = va.y;
            at[lc + 2][r] = va.z; at[lc + 3][r] = va.w;
            const float4 vw = *(const float4*)(W + (size_t)(j0 + r) * DIM + k0 + lc);
            wt[lc + 0][r] = vw.x; wt[lc + 1][r] = vw.y;
            wt[lc + 2][r] = vw.z; wt[lc + 3][r] = vw.w;
        }
        __syncthreads();

        #pragma unroll 8
        for (int kk = 0; kk < BK; ++kk) {
            const float a0 = at[kk][ty * 4 + 0];
            const float a1 = at[kk][ty * 4 + 1];
            const float a2 = at[kk][ty * 4 + 2];
            const float a3 = at[kk][ty * 4 + 3];
            const float b0 = wt[kk][tx * 4 + 0];
            const float b1 = wt[kk][tx * 4 + 1];
            const float b2 = wt[kk][tx * 4 + 2];
            const float b3 = wt[kk][tx * 4 + 3];
            acc[0][0] += a0 * b0; acc[0][1] += a0 * b1; acc[0][2] += a0 * b2; acc[0][3] += a0 * b3;
            acc[1][0] += a1 * b0; acc[1][1] += a1 * b1; acc[1][2] += a1 * b2; acc[1][3] += a1 * b3;
            acc[2][0] += a2 * b0; acc[2][1] += a2 * b1; acc[2][2] += a2 * b2; acc[2][3] += a2 * b3;
            acc[3][0] += a3 * b0; acc[3][1] += a3 * b1; acc[3][2] += a3 * b2; acc[3][3] += a3 * b3;
        }
        __syncthreads();
    }

    #pragma unroll
    for (int i = 0; i < 4; ++i) {
        const int row = m0 + ty * 4 + i;
        const int col = j0 + tx * 4;
        float4 o;
        o.x = acc[i][0]; o.y = acc[i][1]; o.z = acc[i][2]; o.w = acc[i][3];
        if (bias) {
            o.x += bias[col + 0]; o.y += bias[col + 1];
            o.z += bias[col + 2]; o.w += bias[col + 3];
        }
        *(float4*)(outp + (size_t)row * INNER + col) = o;
    }
}

// ---------------------------------------------------------------------------
// Kernel 1: fused q/k/v projections.  qkv layout: [3][NTOK][INNER] fp32
// ---------------------------------------------------------------------------
__global__ __launch_bounds__(256) void proj_kernel(
    const float* __restrict__ x, const float* __restrict__ q,
    const float* __restrict__ wq, const float* __restrict__ wk,
    const float* __restrict__ wv, float* __restrict__ qkv)
{
    __shared__ float at[BK][BM + 4];
    __shared__ float wt[BK][BN + 4];

    const int seg = blockIdx.y >> 2;
    const int jt  = blockIdx.y & 3;
    const float* A = (seg == 0) ? q : x;
    const float* W = (seg == 0) ? wq : ((seg == 1) ? wk : wv);
    float* outp = qkv + (size_t)seg * NTOK * INNER;

    gemm64_tile(A, W, nullptr, outp, blockIdx.x * BM, jt * BN, at, wt);
}

// ---------------------------------------------------------------------------
// Kernel 2: LDS-staged local attention.
// grid = (512 rows, 8 heads), block = 256.
// Row r = ((b*S + s)*H + h); handles 16 tokens (w=0..15) for one head.
// Stage K^T halo slice -> QK dots -> softmax -> stage V (same buffer) -> PV.
// ---------------------------------------------------------------------------
__global__ __launch_bounds__(256) void attn_kernel(
    const float* __restrict__ qkv, float* __restrict__ ao)
{
    __shared__ float kvbuf[NHALO * V_PITCH];   // 300*33 = 9900 f (also 32*301 K^T)
    __shared__ float qs[W_][DH + 1];
    __shared__ float dots[W_][80];
    __shared__ float inv_sum[W_];

    const int r    = blockIdx.x;
    const int head = blockIdx.y;
    const int tid  = threadIdx.x;

    const int h = r & (H_ - 1);
    const int s = (r >> 5) & (S_ - 1);
    const int n_base = r * W_;

    const float* kbase = qkv + (size_t)1 * NTOK * INNER + head * DH;
    const float* vbase = qkv + (size_t)2 * NTOK * INNER + head * DH;
    const float* qbase = qkv + head * DH;

    const int ltok = tid >> 3;        // 0..31  (token within pass)
    const int lelt = (tid & 7) * 4;   // 0,4,..,28

    // ---- phase 1: stage K^T (and q) --------------------------------------
    #pragma unroll
    for (int pass = 0; pass < 10; ++pass) {
        const int ht = pass * 32 + ltok;
        if (ht < NHALO) {
            const int ds  = ht / 100;
            const int rem = ht - ds * 100;
            const int dh  = rem / HW;
            const int hw  = rem - dh * HW;
            const int s2 = s + ds - 1, h2 = h + dh - 2, w2 = hw - 2;
            float4 v = make_float4(0.f, 0.f, 0.f, 0.f);
            if (((unsigned)s2 < S_) && ((unsigned)h2 < H_) && ((unsigned)w2 < W_)) {
                const int nn = n_base + ((s2 - s) * H_ + (h2 - h)) * W_ + w2;
                v = *(const float4*)(kbase + (size_t)nn * INNER + lelt);
            }
            kvbuf[(lelt + 0) * KT_PITCH + ht] = v.x;
            kvbuf[(lelt + 1) * KT_PITCH + ht] = v.y;
            kvbuf[(lelt + 2) * KT_PITCH + ht] = v.z;
            kvbuf[(lelt + 3) * KT_PITCH + ht] = v.w;
        }
    }
    if (tid < W_ * 8) {   // 16 tokens * 8 float4 = q tile
        const int tok = tid >> 3;
        const float4 v = *(const float4*)(qbase + (size_t)(n_base + tok) * INNER + lelt);
        qs[tok][lelt + 0] = v.x; qs[tok][lelt + 1] = v.y;
        qs[tok][lelt + 2] = v.z; qs[tok][lelt + 3] = v.w;
    }
    __syncthreads();

    // ---- phase 2: QK dots -------------------------------------------------
    const float scale = 0.17677669529663687f;  // 32^-0.5
    #pragma unroll
    for (int pass = 0; pass < 5; ++pass) {
        const int t = pass * 256 + tid;
        if (t < W_ * WIN) {
            const int tok = t / WIN;
            const int wi  = t - tok * WIN;
            const int ds  = wi / 25;
            const int rem = wi - ds * 25;
            const int dh  = rem / 5;
            const int dw  = rem - dh * 5;
            const int hidx = (ds * HH + dh) * HW + tok + dw;
            const bool valid = ((unsigned)(s + ds - 1) < S_) &&
                               ((unsigned)(h + dh - 2) < H_) &&
                               ((unsigned)(tok + dw - 2) < W_);
            float a = 0.f;
            #pragma unroll
            for (int dd = 0; dd < DH; ++dd)
                a += qs[tok][dd] * kvbuf[dd * KT_PITCH + hidx];
            dots[tok][wi] = valid ? a * scale : -1e9f;
        }
    }
    __syncthreads();

    // ---- phase 3: stage V (overwrites K) + softmax ------------------------
    // V staging loads are issued first so they overlap the softmax math.
    float4 vstage[10];
    int    vht[10];
    #pragma unroll
    for (int pass = 0; pass < 10; ++pass) {
        const int ht = pass * 32 + ltok;
        vht[pass] = -1;
        if (ht < NHALO) {
            const int ds  = ht / 100;
            const int rem = ht - ds * 100;
            const int dh  = rem / HW;
            const int hw  = rem - dh * HW;
            const int s2 = s + ds - 1, h2 = h + dh - 2, w2 = hw - 2;
            float4 v = make_float4(0.f, 0.f, 0.f, 0.f);
            if (((unsigned)s2 < S_) && ((unsigned)h2 < H_) && ((unsigned)w2 < W_)) {
                const int nn = n_base + ((s2 - s) * H_ + (h2 - h)) * W_ + w2;
                v = *(const float4*)(vbase + (size_t)nn * INNER + lelt);
            }
            vstage[pass] = v;
            vht[pass] = ht;
        }
    }

    {   // softmax: 16 tokens x 16 lanes
        const int tok = tid >> 4, l = tid & 15;
        float v[5];
        #pragma unroll
        for (int i = 0; i < 5; ++i) {
            const int idx = l + 16 * i;
            v[i] = (idx < WIN) ? dots[tok][idx] : -1e9f;
        }
        float m = v[0];
        #pragma unroll
        for (int i = 1; i < 5; ++i) m = fmaxf(m, v[i]);
        #pragma unroll
        for (int off = 8; off; off >>= 1) m = fmaxf(m, __shfl_xor(m, off, 16));
        float e[5], sum = 0.f;
        #pragma unroll
        for (int i = 0; i < 5; ++i) { e[i] = __expf(v[i] - m); sum += e[i]; }
        #pragma unroll
        for (int off = 8; off; off >>= 1) sum += __shfl_xor(sum, off, 16);
        #pragma unroll
        for (int i = 0; i < 5; ++i) {
            const int idx = l + 16 * i;
            if (idx < WIN) dots[tok][idx] = e[i];
        }
        if (l == 0) inv_sum[tok] = 1.f / sum;
    }
    __syncthreads();   // K reads done (phase 2 barrier), dots/exp published

    // now commit V into LDS
    #pragma unroll
    for (int pass = 0; pass < 10; ++pass) {
        if (vht[pass] >= 0) {
            const int ht = vht[pass];
            const float4 v = vstage[pass];
            kvbuf[ht * V_PITCH + lelt + 0] = v.x;
            kvbuf[ht * V_PITCH + lelt + 1] = v.y;
            kvbuf[ht * V_PITCH + lelt + 2] = v.z;
            kvbuf[ht * V_PITCH + lelt + 3] = v.w;
        }
    }
    __syncthreads();

    // ---- phase 4: PV ------------------------------------------------------
    #pragma unroll
    for (int pass = 0; pass < 2; ++pass) {
        const int tok = (tid >> 5) + pass * 8;
        const int d   = tid & 31;
        float acc = 0.f;
        #pragma unroll
        for (int ds = 0; ds < HS; ++ds) {
            #pragma unroll
            for (int dh = 0; dh < HH; ++dh) {
                const int hbase = (ds * HH + dh) * HW + tok;
                const int wbase = (ds * HH + dh) * 5;
                #pragma unroll
                for (int dw = 0; dw < 5; ++dw) {
                    acc += dots[tok][wbase + dw] * kvbuf[(hbase + dw) * V_PITCH + d];
                }
            }
        }
        ao[(size_t)(n_base + tok) * INNER + head * DH + d] = acc * inv_sum[tok];
    }
}

// ---------------------------------------------------------------------------
// Kernel 3: output projection: out = ao @ wo^T + bo
// ---------------------------------------------------------------------------
__global__ __launch_bounds__(256) void outproj_kernel(
    const float* __restrict__ ao, const float* __restrict__ wo,
    const float* __restrict__ bo, float* __restrict__ out)
{
    __shared__ float at[BK][BM + 4];
    __shared__ float wt[BK][BN + 4];
    gemm64_tile(ao, wo, bo, out, blockIdx.x * BM, blockIdx.y * BN, at, wt);
}

// ---------------------------------------------------------------------------
extern "C" void kernel_launch(void* const* d_in, const int* in_sizes, int n_in,
                              void* d_out, int out_size, void* d_ws, size_t ws_size,
                              hipStream_t stream) {
    const float* x  = (const float*)d_in[0];
    const float* q  = (const float*)d_in[1];
    const float* wq = (const float*)d_in[2];
    const float* wk = (const float*)d_in[3];
    const float* wv = (const float*)d_in[4];
    const float* wo = (const float*)d_in[5];
    const float* bo = (const float*)d_in[6];
    float* out = (float*)d_out;

    float* qkv = (float*)d_ws;
    float* ao  = qkv + (size_t)3 * NTOK * INNER;

    dim3 g1(NTOK / BM, 12);
    proj_kernel<<<g1, 256, 0, stream>>>(x, q, wq, wk, wv, qkv);

    dim3 g2(NTOK / W_, HEADS);
    attn_kernel<<<g2, 256, 0, stream>>>(qkv, ao);

    dim3 g3(NTOK / BM, INNER / BN);
    outproj_kernel<<<g3, 256, 0, stream>>>(ao, wo, bo, out);
}

// Round 3
// 98.061 us; speedup vs baseline: 2.0091x; 1.4487x over previous
//
#include <hip/hip_runtime.h>
#include <hip/hip_bf16.h>
#include <math.h>

#define HEADS 8
#define DH 32
#define DIM 256
#define INNER 256
#define B_ 2
#define S_ 8
#define H_ 32
#define W_ 16
#define NTOK (B_*S_*H_*W_)   /* 8192 */
#define WIN 75

// halo geometry for one (b,s,h) row of 16 tokens
#define HS 3
#define HH 5
#define HW 20
#define NHALO (HS*HH*HW)     /* 300 */
#define KT_PITCH 301         /* K^T row stride (floats) — conflict-free */
#define V_PITCH 33           /* V row stride (floats) */

typedef _Float16 h16;
typedef h16 half8 __attribute__((ext_vector_type(8)));
typedef float f32x4 __attribute__((ext_vector_type(4)));

// ---------------------------------------------------------------------------
// MFMA f16 GEMM: out[m][j] = sum_k A[m][k] * W[j][k]   (K = 256)
// Block: 256 thr = 4 waves in 2x2 wave grid; tile 128(M) x 64(N); BK = 32.
// LDS staged as f16, pitch 40 (2-way bank alias = free).
// A/B frag: lane l -> row/col = l&15, k = (l>>4)*8 + e (k-contiguous, m97).
// C/D frag: col = l&15, row = (l>>4)*4 + reg (m89).
// ---------------------------------------------------------------------------
#define GBM 128
#define GBN 64
#define GBK 32
#define GPITCH 40

__device__ __forceinline__ uint4 cvt8(const float4 a, const float4 b) {
    union { h16 h[8]; uint4 u; } p;
    p.h[0] = (h16)a.x; p.h[1] = (h16)a.y; p.h[2] = (h16)a.z; p.h[3] = (h16)a.w;
    p.h[4] = (h16)b.x; p.h[5] = (h16)b.y; p.h[6] = (h16)b.z; p.h[7] = (h16)b.w;
    return p.u;
}

__device__ __forceinline__ void mfma_gemm_tile(
    const float* __restrict__ A, const float* __restrict__ W,
    const float* __restrict__ bias, float* __restrict__ outp,
    int m0, int j0, h16* aT, h16* bT)
{
    const int tid  = threadIdx.x;
    const int lane = tid & 63;
    const int wid  = tid >> 6;
    const int wr   = wid >> 1;       // 0..1  (M half)
    const int wc   = wid & 1;        // 0..1  (N half)
    const int r    = lane & 15;
    const int g    = lane >> 4;      // k-group

    f32x4 acc[4][2];
    #pragma unroll
    for (int i = 0; i < 4; ++i)
        #pragma unroll
        for (int j = 0; j < 2; ++j)
            acc[i][j] = (f32x4){0.f, 0.f, 0.f, 0.f};

    const int arow = tid >> 1;          // 0..127
    const int ahalf = (tid & 1) * 16;   // 0 or 16 (k offset)
    const int brow = (tid & 127) >> 1;  // 0..63
    const bool doB = tid < 128;

    for (int k0 = 0; k0 < DIM; k0 += GBK) {
        // ---- stage A (128x32) and B (64x32) as f16 ----
        {
            const float* src = A + (size_t)(m0 + arow) * DIM + k0 + ahalf;
            const float4 u0 = *(const float4*)(src + 0);
            const float4 u1 = *(const float4*)(src + 4);
            const float4 u2 = *(const float4*)(src + 8);
            const float4 u3 = *(const float4*)(src + 12);
            *(uint4*)(aT + arow * GPITCH + ahalf + 0) = cvt8(u0, u1);
            *(uint4*)(aT + arow * GPITCH + ahalf + 8) = cvt8(u2, u3);
        }
        if (doB) {
            const float* src = W + (size_t)(j0 + brow) * DIM + k0 + ahalf;
            const float4 u0 = *(const float4*)(src + 0);
            const float4 u1 = *(const float4*)(src + 4);
            const float4 u2 = *(const float4*)(src + 8);
            const float4 u3 = *(const float4*)(src + 12);
            *(uint4*)(bT + brow * GPITCH + ahalf + 0) = cvt8(u0, u1);
            *(uint4*)(bT + brow * GPITCH + ahalf + 8) = cvt8(u2, u3);
        }
        __syncthreads();

        // ---- fragments + MFMA ----
        half8 af[4], bf[2];
        #pragma unroll
        for (int fr = 0; fr < 4; ++fr)
            af[fr] = *(const half8*)(aT + (wr * 64 + fr * 16 + r) * GPITCH + g * 8);
        #pragma unroll
        for (int fc = 0; fc < 2; ++fc)
            bf[fc] = *(const half8*)(bT + (wc * 32 + fc * 16 + r) * GPITCH + g * 8);

        #pragma unroll
        for (int fr = 0; fr < 4; ++fr)
            #pragma unroll
            for (int fc = 0; fc < 2; ++fc)
                acc[fr][fc] = __builtin_amdgcn_mfma_f32_16x16x32_f16(
                    af[fr], bf[fc], acc[fr][fc], 0, 0, 0);
        __syncthreads();
    }

    // ---- epilogue ----
    #pragma unroll
    for (int fr = 0; fr < 4; ++fr) {
        #pragma unroll
        for (int fc = 0; fc < 2; ++fc) {
            const int col = j0 + wc * 32 + fc * 16 + r;
            const float badd = bias ? bias[col] : 0.f;
            #pragma unroll
            for (int i = 0; i < 4; ++i) {
                const int row = m0 + wr * 64 + fr * 16 + g * 4 + i;
                outp[(size_t)row * INNER + col] = acc[fr][fc][i] + badd;
            }
        }
    }
}

// ---------------------------------------------------------------------------
// Kernel 1: fused q/k/v projections.  qkv layout: [3][NTOK][INNER] fp32
// grid = (8192/128, 12) = (64, 12);  y: seg = y>>2, n-tile = y&3
// ---------------------------------------------------------------------------
__global__ __launch_bounds__(256) void proj_kernel(
    const float* __restrict__ x, const float* __restrict__ q,
    const float* __restrict__ wq, const float* __restrict__ wk,
    const float* __restrict__ wv, float* __restrict__ qkv)
{
    __shared__ h16 aT[GBM * GPITCH];
    __shared__ h16 bT[GBN * GPITCH];

    const int seg = blockIdx.y >> 2;
    const int jt  = blockIdx.y & 3;
    const float* A = (seg == 0) ? q : x;
    const float* W = (seg == 0) ? wq : ((seg == 1) ? wk : wv);
    float* outp = qkv + (size_t)seg * NTOK * INNER;

    mfma_gemm_tile(A, W, nullptr, outp, blockIdx.x * GBM, jt * GBN, aT, bT);
}

// ---------------------------------------------------------------------------
// Kernel 2: LDS-staged local attention (unchanged from R2 — A/B isolation).
// ---------------------------------------------------------------------------
__global__ __launch_bounds__(256) void attn_kernel(
    const float* __restrict__ qkv, float* __restrict__ ao)
{
    __shared__ float kvbuf[NHALO * V_PITCH];
    __shared__ float qs[W_][DH + 1];
    __shared__ float dots[W_][80];
    __shared__ float inv_sum[W_];

    const int r    = blockIdx.x;
    const int head = blockIdx.y;
    const int tid  = threadIdx.x;

    const int h = r & (H_ - 1);
    const int s = (r >> 5) & (S_ - 1);
    const int n_base = r * W_;

    const float* kbase = qkv + (size_t)1 * NTOK * INNER + head * DH;
    const float* vbase = qkv + (size_t)2 * NTOK * INNER + head * DH;
    const float* qbase = qkv + head * DH;

    const int ltok = tid >> 3;
    const int lelt = (tid & 7) * 4;

    // ---- phase 1: stage K^T (and q) --------------------------------------
    #pragma unroll
    for (int pass = 0; pass < 10; ++pass) {
        const int ht = pass * 32 + ltok;
        if (ht < NHALO) {
            const int ds  = ht / 100;
            const int rem = ht - ds * 100;
            const int dh  = rem / HW;
            const int hw  = rem - dh * HW;
            const int s2 = s + ds - 1, h2 = h + dh - 2, w2 = hw - 2;
            float4 v = make_float4(0.f, 0.f, 0.f, 0.f);
            if (((unsigned)s2 < S_) && ((unsigned)h2 < H_) && ((unsigned)w2 < W_)) {
                const int nn = n_base + ((s2 - s) * H_ + (h2 - h)) * W_ + w2;
                v = *(const float4*)(kbase + (size_t)nn * INNER + lelt);
            }
            kvbuf[(lelt + 0) * KT_PITCH + ht] = v.x;
            kvbuf[(lelt + 1) * KT_PITCH + ht] = v.y;
            kvbuf[(lelt + 2) * KT_PITCH + ht] = v.z;
            kvbuf[(lelt + 3) * KT_PITCH + ht] = v.w;
        }
    }
    if (tid < W_ * 8) {
        const int tok = tid >> 3;
        const float4 v = *(const float4*)(qbase + (size_t)(n_base + tok) * INNER + lelt);
        qs[tok][lelt + 0] = v.x; qs[tok][lelt + 1] = v.y;
        qs[tok][lelt + 2] = v.z; qs[tok][lelt + 3] = v.w;
    }
    __syncthreads();

    // ---- phase 2: QK dots -------------------------------------------------
    const float scale = 0.17677669529663687f;
    #pragma unroll
    for (int pass = 0; pass < 5; ++pass) {
        const int t = pass * 256 + tid;
        if (t < W_ * WIN) {
            const int tok = t / WIN;
            const int wi  = t - tok * WIN;
            const int ds  = wi / 25;
            const int rem = wi - ds * 25;
            const int dh  = rem / 5;
            const int dw  = rem - dh * 5;
            const int hidx = (ds * HH + dh) * HW + tok + dw;
            const bool valid = ((unsigned)(s + ds - 1) < S_) &&
                               ((unsigned)(h + dh - 2) < H_) &&
                               ((unsigned)(tok + dw - 2) < W_);
            float a = 0.f;
            #pragma unroll
            for (int dd = 0; dd < DH; ++dd)
                a += qs[tok][dd] * kvbuf[dd * KT_PITCH + hidx];
            dots[tok][wi] = valid ? a * scale : -1e9f;
        }
    }
    __syncthreads();

    // ---- phase 3: stage V (overwrites K) + softmax ------------------------
    float4 vstage[10];
    int    vht[10];
    #pragma unroll
    for (int pass = 0; pass < 10; ++pass) {
        const int ht = pass * 32 + ltok;
        vht[pass] = -1;
        if (ht < NHALO) {
            const int ds  = ht / 100;
            const int rem = ht - ds * 100;
            const int dh  = rem / HW;
            const int hw  = rem - dh * HW;
            const int s2 = s + ds - 1, h2 = h + dh - 2, w2 = hw - 2;
            float4 v = make_float4(0.f, 0.f, 0.f, 0.f);
            if (((unsigned)s2 < S_) && ((unsigned)h2 < H_) && ((unsigned)w2 < W_)) {
                const int nn = n_base + ((s2 - s) * H_ + (h2 - h)) * W_ + w2;
                v = *(const float4*)(vbase + (size_t)nn * INNER + lelt);
            }
            vstage[pass] = v;
            vht[pass] = ht;
        }
    }

    {   // softmax: 16 tokens x 16 lanes
        const int tok = tid >> 4, l = tid & 15;
        float v[5];
        #pragma unroll
        for (int i = 0; i < 5; ++i) {
            const int idx = l + 16 * i;
            v[i] = (idx < WIN) ? dots[tok][idx] : -1e9f;
        }
        float m = v[0];
        #pragma unroll
        for (int i = 1; i < 5; ++i) m = fmaxf(m, v[i]);
        #pragma unroll
        for (int off = 8; off; off >>= 1) m = fmaxf(m, __shfl_xor(m, off, 16));
        float e[5], sum = 0.f;
        #pragma unroll
        for (int i = 0; i < 5; ++i) { e[i] = __expf(v[i] - m); sum += e[i]; }
        #pragma unroll
        for (int off = 8; off; off >>= 1) sum += __shfl_xor(sum, off, 16);
        #pragma unroll
        for (int i = 0; i < 5; ++i) {
            const int idx = l + 16 * i;
            if (idx < WIN) dots[tok][idx] = e[i];
        }
        if (l == 0) inv_sum[tok] = 1.f / sum;
    }
    __syncthreads();

    #pragma unroll
    for (int pass = 0; pass < 10; ++pass) {
        if (vht[pass] >= 0) {
            const int ht = vht[pass];
            const float4 v = vstage[pass];
            kvbuf[ht * V_PITCH + lelt + 0] = v.x;
            kvbuf[ht * V_PITCH + lelt + 1] = v.y;
            kvbuf[ht * V_PITCH + lelt + 2] = v.z;
            kvbuf[ht * V_PITCH + lelt + 3] = v.w;
        }
    }
    __syncthreads();

    // ---- phase 4: PV ------------------------------------------------------
    #pragma unroll
    for (int pass = 0; pass < 2; ++pass) {
        const int tok = (tid >> 5) + pass * 8;
        const int d   = tid & 31;
        float acc = 0.f;
        #pragma unroll
        for (int ds = 0; ds < HS; ++ds) {
            #pragma unroll
            for (int dh = 0; dh < HH; ++dh) {
                const int hbase = (ds * HH + dh) * HW + tok;
                const int wbase = (ds * HH + dh) * 5;
                #pragma unroll
                for (int dw = 0; dw < 5; ++dw) {
                    acc += dots[tok][wbase + dw] * kvbuf[(hbase + dw) * V_PITCH + d];
                }
            }
        }
        ao[(size_t)(n_base + tok) * INNER + head * DH + d] = acc * inv_sum[tok];
    }
}

// ---------------------------------------------------------------------------
// Kernel 3: output projection: out = ao @ wo^T + bo    grid = (64, 4)
// ---------------------------------------------------------------------------
__global__ __launch_bounds__(256) void outproj_kernel(
    const float* __restrict__ ao, const float* __restrict__ wo,
    const float* __restrict__ bo, float* __restrict__ out)
{
    __shared__ h16 aT[GBM * GPITCH];
    __shared__ h16 bT[GBN * GPITCH];
    mfma_gemm_tile(ao, wo, bo, out, blockIdx.x * GBM, blockIdx.y * GBN, aT, bT);
}

// ---------------------------------------------------------------------------
extern "C" void kernel_launch(void* const* d_in, const int* in_sizes, int n_in,
                              void* d_out, int out_size, void* d_ws, size_t ws_size,
                              hipStream_t stream) {
    const float* x  = (const float*)d_in[0];
    const float* q  = (const float*)d_in[1];
    const float* wq = (const float*)d_in[2];
    const float* wk = (const float*)d_in[3];
    const float* wv = (const float*)d_in[4];
    const float* wo = (const float*)d_in[5];
    const float* bo = (const float*)d_in[6];
    float* out = (float*)d_out;

    float* qkv = (float*)d_ws;
    float* ao  = qkv + (size_t)3 * NTOK * INNER;

    dim3 g1(NTOK / GBM, 12);
    proj_kernel<<<g1, 256, 0, stream>>>(x, q, wq, wk, wv, qkv);

    dim3 g2(NTOK / W_, HEADS);
    attn_kernel<<<g2, 256, 0, stream>>>(qkv, ao);

    dim3 g3(NTOK / GBM, INNER / GBN);
    outproj_kernel<<<g3, 256, 0, stream>>>(ao, wo, bo, out);
}

// Round 4
// 54.420 us; speedup vs baseline: 3.6201x; 1.8019x over previous
//
#include <hip/hip_runtime.h>
#include <hip/hip_bf16.h>
#include <math.h>

#define HEADS 8
#define DH 32
#define DIM 256
#define INNER 256
#define B_ 2
#define S_ 8
#define H_ 32
#define W_ 16
#define NTOK (B_*S_*H_*W_)   /* 8192 */

typedef _Float16 h16;
typedef h16 half8 __attribute__((ext_vector_type(8)));
typedef float f32x4 __attribute__((ext_vector_type(4)));

// ---------------------------------------------------------------------------
// MFMA f16 GEMM: out[m][j] = sum_k A[m][k] * W[j][k]   (K = 256)
// 256 thr = 4 waves (2x2); tile 128x64; BK=32. Layouts HW-validated in R3.
// ---------------------------------------------------------------------------
#define GBM 128
#define GBN 64
#define GBK 32
#define GPITCH 40

__device__ __forceinline__ uint4 cvt8(const float4 a, const float4 b) {
    union { h16 h[8]; uint4 u; } p;
    p.h[0] = (h16)a.x; p.h[1] = (h16)a.y; p.h[2] = (h16)a.z; p.h[3] = (h16)a.w;
    p.h[4] = (h16)b.x; p.h[5] = (h16)b.y; p.h[6] = (h16)b.z; p.h[7] = (h16)b.w;
    return p.u;
}

template <bool A_F16, bool OUT_F16>
__device__ __forceinline__ void mfma_gemm_tile_t(
    const void* __restrict__ Av, const float* __restrict__ W,
    const float* __restrict__ bias, void* __restrict__ outv,
    int m0, int j0, h16* aT, h16* bT)
{
    const int tid  = threadIdx.x;
    const int lane = tid & 63;
    const int wid  = tid >> 6;
    const int wr   = wid >> 1;
    const int wc   = wid & 1;
    const int r    = lane & 15;
    const int g    = lane >> 4;

    f32x4 acc[4][2];
    #pragma unroll
    for (int i = 0; i < 4; ++i)
        #pragma unroll
        for (int j = 0; j < 2; ++j)
            acc[i][j] = (f32x4){0.f, 0.f, 0.f, 0.f};

    const int arow  = tid >> 1;
    const int ahalf = (tid & 1) * 16;
    const int brow  = (tid & 127) >> 1;
    const bool doB  = tid < 128;

    for (int k0 = 0; k0 < DIM; k0 += GBK) {
        if constexpr (A_F16) {
            const h16* A = (const h16*)Av;
            const h16* src = A + (size_t)(m0 + arow) * DIM + k0 + ahalf;
            *(uint4*)(aT + arow * GPITCH + ahalf + 0) = *(const uint4*)(src + 0);
            *(uint4*)(aT + arow * GPITCH + ahalf + 8) = *(const uint4*)(src + 8);
        } else {
            const float* A = (const float*)Av;
            const float* src = A + (size_t)(m0 + arow) * DIM + k0 + ahalf;
            const float4 u0 = *(const float4*)(src + 0);
            const float4 u1 = *(const float4*)(src + 4);
            const float4 u2 = *(const float4*)(src + 8);
            const float4 u3 = *(const float4*)(src + 12);
            *(uint4*)(aT + arow * GPITCH + ahalf + 0) = cvt8(u0, u1);
            *(uint4*)(aT + arow * GPITCH + ahalf + 8) = cvt8(u2, u3);
        }
        if (doB) {
            const float* src = W + (size_t)(j0 + brow) * DIM + k0 + ahalf;
            const float4 u0 = *(const float4*)(src + 0);
            const float4 u1 = *(const float4*)(src + 4);
            const float4 u2 = *(const float4*)(src + 8);
            const float4 u3 = *(const float4*)(src + 12);
            *(uint4*)(bT + brow * GPITCH + ahalf + 0) = cvt8(u0, u1);
            *(uint4*)(bT + brow * GPITCH + ahalf + 8) = cvt8(u2, u3);
        }
        __syncthreads();

        half8 af[4], bf[2];
        #pragma unroll
        for (int fr = 0; fr < 4; ++fr)
            af[fr] = *(const half8*)(aT + (wr * 64 + fr * 16 + r) * GPITCH + g * 8);
        #pragma unroll
        for (int fc = 0; fc < 2; ++fc)
            bf[fc] = *(const half8*)(bT + (wc * 32 + fc * 16 + r) * GPITCH + g * 8);

        #pragma unroll
        for (int fr = 0; fr < 4; ++fr)
            #pragma unroll
            for (int fc = 0; fc < 2; ++fc)
                acc[fr][fc] = __builtin_amdgcn_mfma_f32_16x16x32_f16(
                    af[fr], bf[fc], acc[fr][fc], 0, 0, 0);
        __syncthreads();
    }

    #pragma unroll
    for (int fr = 0; fr < 4; ++fr) {
        #pragma unroll
        for (int fc = 0; fc < 2; ++fc) {
            const int col = j0 + wc * 32 + fc * 16 + r;
            const float badd = bias ? bias[col] : 0.f;
            #pragma unroll
            for (int i = 0; i < 4; ++i) {
                const int row = m0 + wr * 64 + fr * 16 + g * 4 + i;
                const float val = acc[fr][fc][i] + badd;
                if constexpr (OUT_F16)
                    ((h16*)outv)[(size_t)row * INNER + col] = (h16)val;
                else
                    ((float*)outv)[(size_t)row * INNER + col] = val;
            }
        }
    }
}

// ---------------------------------------------------------------------------
// Kernel 1: q/k/v projections -> qkv f16 [3][NTOK][INNER]
// ---------------------------------------------------------------------------
__global__ __launch_bounds__(256) void proj_kernel(
    const float* __restrict__ x, const float* __restrict__ q,
    const float* __restrict__ wq, const float* __restrict__ wk,
    const float* __restrict__ wv, h16* __restrict__ qkv)
{
    __shared__ h16 aT[GBM * GPITCH];
    __shared__ h16 bT[GBN * GPITCH];

    const int seg = blockIdx.y >> 2;
    const int jt  = blockIdx.y & 3;
    const float* A = (seg == 0) ? q : x;
    const float* W = (seg == 0) ? wq : ((seg == 1) ? wk : wv);
    h16* outp = qkv + (size_t)seg * NTOK * INNER;

    mfma_gemm_tile_t<false, true>(A, W, nullptr, outp, blockIdx.x * GBM, jt * GBN, aT, bT);
}

// ---------------------------------------------------------------------------
// Kernel 2: MFMA local attention. grid = (512 rows, 2 head-quads), 256 thr.
// Wave w handles head hq*4+w for one (b,s,h) row of 16 tokens.
// Halo = 3x5x20 = 300 (+pad to 320). nn-table in LDS; K/V frags gathered
// directly from global; P routed through per-wave LDS slab.
// ---------------------------------------------------------------------------
#define NHE 320      /* padded halo entries */
#define PP  328      /* P slab pitch (f16) */

__global__ __launch_bounds__(256) void attn_kernel(
    const h16* __restrict__ qkv, h16* __restrict__ ao)
{
    __shared__ int nn_lds[NHE];
    __shared__ h16 P_lds[4][16 * PP];

    const int r_raw = blockIdx.x;
    const int r     = ((r_raw & 7) << 6) | (r_raw >> 3);   // XCD-contiguous rows
    const int hq    = blockIdx.y;
    const int tid   = threadIdx.x;
    const int lane  = tid & 63;
    const int wid   = tid >> 6;
    const int head  = hq * 4 + wid;

    const int h = r & 31, s = (r >> 5) & 7, b = r >> 8;
    const int n_base = r * 16;

    // ---- build halo table: ent = nn | hw<<16 | inb<<24 --------------------
    for (int ht = tid; ht < NHE; ht += 256) {
        int ent = 0;
        if (ht < 300) {
            const int ds  = ht / 100;
            const int rem = ht - ds * 100;
            const int hh  = rem / 20;
            const int hw  = rem - hh * 20;
            const int s2 = s + ds - 1, h2 = h + hh - 2, w2 = hw - 2;
            const bool inb = ((unsigned)s2 < 8) && ((unsigned)h2 < 32) && ((unsigned)w2 < 16);
            const int s2c = min(max(s2, 0), 7);
            const int h2c = min(max(h2, 0), 31);
            const int w2c = min(max(w2, 0), 15);
            const int nn  = ((b * 8 + s2c) * 32 + h2c) * 16 + w2c;
            ent = nn | (hw << 16) | (inb ? (1 << 24) : 0);
        }
        nn_lds[ht] = ent;
    }
    __syncthreads();
    // waves are independent from here on (own head, own P slab)

    h16* P = &P_lds[wid][0];
    const int c  = lane & 15;
    const int g  = lane >> 4;
    const int q0 = g * 4;

    // zero P pad cols 304..319
    *(uint2*)(P + (lane >> 2) * PP + 304 + (lane & 3) * 4) = (uint2){0u, 0u};

    const h16*    kb  = qkv + (size_t)1 * NTOK * INNER;
    const ushort* vbu = (const ushort*)(qkv + (size_t)2 * NTOK * INNER);

    // Q fragment: row q = c, k = g*8..g*8+7
    const half8 qf = *(const half8*)(qkv + (size_t)(n_base + c) * INNER + head * DH + g * 8);

    // ---- QK: 19 tiles of 16 halo cols -------------------------------------
    f32x4 dots[19];
    #pragma unroll
    for (int t = 0; t < 19; ++t) {
        const int ent = nn_lds[16 * t + c];
        const int nn  = ent & 0xffff;
        const half8 kf = *(const half8*)(kb + (size_t)nn * INNER + head * DH + g * 8);
        dots[t] = __builtin_amdgcn_mfma_f32_16x16x32_f16(qf, kf, (f32x4){0.f,0.f,0.f,0.f}, 0, 0, 0);
    }

    // ---- mask into dots (invalid -> -1e30), masked max --------------------
    float mx[4] = {-1e30f, -1e30f, -1e30f, -1e30f};
    #pragma unroll
    for (int t = 0; t < 19; ++t) {
        const int ent = nn_lds[16 * t + c];
        const int hw  = (ent >> 16) & 31;
        const int inb = ent >> 24;
        #pragma unroll
        for (int i = 0; i < 4; ++i) {
            const unsigned dwq = (unsigned)(hw - (q0 + i));
            const bool ok = inb && (dwq <= 4u);
            const float dv = ok ? dots[t][i] : -1e30f;
            dots[t][i] = dv;
            mx[i] = fmaxf(mx[i], dv);
        }
    }
    #pragma unroll
    for (int off = 8; off; off >>= 1)
        #pragma unroll
        for (int i = 0; i < 4; ++i)
            mx[i] = fmaxf(mx[i], __shfl_xor(mx[i], off));

    // ---- exp, sum, write P ------------------------------------------------
    const float scale = 0.17677669529663687f;   // 32^-0.5
    float sum[4] = {0.f, 0.f, 0.f, 0.f};
    #pragma unroll
    for (int t = 0; t < 19; ++t) {
        #pragma unroll
        for (int i = 0; i < 4; ++i) {
            const float e = __expf((dots[t][i] - mx[i]) * scale);
            sum[i] += e;
            P[(q0 + i) * PP + 16 * t + c] = (h16)e;
        }
    }
    #pragma unroll
    for (int off = 8; off; off >>= 1)
        #pragma unroll
        for (int i = 0; i < 4; ++i)
            sum[i] += __shfl_xor(sum[i], off);
    float inv[4];
    #pragma unroll
    for (int i = 0; i < 4; ++i) inv[i] = 1.f / sum[i];

    // ---- PV: 10 k-chunks of 32, 2 d-tiles ---------------------------------
    f32x4 o0 = (f32x4){0.f,0.f,0.f,0.f};
    f32x4 o1 = (f32x4){0.f,0.f,0.f,0.f};
    #pragma unroll
    for (int ch = 0; ch < 10; ++ch) {
        const half8 pf = *(const half8*)(P + c * PP + ch * 32 + g * 8);
        int ents[8];
        #pragma unroll
        for (int e = 0; e < 8; ++e) ents[e] = nn_lds[ch * 32 + g * 8 + e];
        union { ushort u[8]; half8 hv; } v0f, v1f;
        #pragma unroll
        for (int e = 0; e < 8; ++e) {
            const ushort* vp = vbu + (size_t)(ents[e] & 0xffff) * INNER + head * DH + c;
            v0f.u[e] = vp[0];
            v1f.u[e] = vp[16];
        }
        o0 = __builtin_amdgcn_mfma_f32_16x16x32_f16(pf, v0f.hv, o0, 0, 0, 0);
        o1 = __builtin_amdgcn_mfma_f32_16x16x32_f16(pf, v1f.hv, o1, 0, 0, 0);
    }

    // ---- write out (f16) --------------------------------------------------
    #pragma unroll
    for (int i = 0; i < 4; ++i) {
        const size_t row = (size_t)(n_base + q0 + i) * INNER + head * DH;
        ao[row + c]      = (h16)(o0[i] * inv[i]);
        ao[row + 16 + c] = (h16)(o1[i] * inv[i]);
    }
}

// ---------------------------------------------------------------------------
// Kernel 3: out = ao(f16) @ wo^T + bo   grid = (64, 4)
// ---------------------------------------------------------------------------
__global__ __launch_bounds__(256) void outproj_kernel(
    const h16* __restrict__ ao, const float* __restrict__ wo,
    const float* __restrict__ bo, float* __restrict__ out)
{
    __shared__ h16 aT[GBM * GPITCH];
    __shared__ h16 bT[GBN * GPITCH];
    mfma_gemm_tile_t<true, false>(ao, wo, bo, out, blockIdx.x * GBM, blockIdx.y * GBN, aT, bT);
}

// ---------------------------------------------------------------------------
extern "C" void kernel_launch(void* const* d_in, const int* in_sizes, int n_in,
                              void* d_out, int out_size, void* d_ws, size_t ws_size,
                              hipStream_t stream) {
    const float* x  = (const float*)d_in[0];
    const float* q  = (const float*)d_in[1];
    const float* wq = (const float*)d_in[2];
    const float* wk = (const float*)d_in[3];
    const float* wv = (const float*)d_in[4];
    const float* wo = (const float*)d_in[5];
    const float* bo = (const float*)d_in[6];
    float* out = (float*)d_out;

    // workspace: qkv f16 [3][8192][256] (12.6 MB) + ao f16 [8192][256] (4.2 MB)
    h16* qkv = (h16*)d_ws;
    h16* ao  = qkv + (size_t)3 * NTOK * INNER;

    dim3 g1(NTOK / GBM, 12);
    proj_kernel<<<g1, 256, 0, stream>>>(x, q, wq, wk, wv, qkv);

    dim3 g2(NTOK / W_, 2);
    attn_kernel<<<g2, 256, 0, stream>>>(qkv, ao);

    dim3 g3(NTOK / GBM, INNER / GBN);
    outproj_kernel<<<g3, 256, 0, stream>>>(ao, wo, bo, out);
}